// Round 7
// baseline (471.588 us; speedup 1.0000x reference)
//
#include <hip/hip_runtime.h>

// VQ-VAE forward: out = code_out[argmax_c(logits_c(x))], hard_idx = argmax.
// logits are piecewise-linear in scalar x (128 relu breakpoints). Build the
// per-interval UPPER ENVELOPE of the 512 affine logit lines (fp64-exact,
// branchless pairwise L/U-bound formulation), flatten to one global x-sorted
// segment table + 4096-bucket accelerator, then O(1) per-sample lookup.
// R7: one ordinary kernel + HAND-ROLLED grid barrier (monotone counter,
// device-scope atomics). R6 lesson: cg::grid.sync() costs ~50us each on
// gfx950; a flat atomic barrier is ~2us. Co-residency by capacity: 512
// blocks, 17.4KB LDS (<=3 blk/CU), 36 VGPR -> capacity >= 768 > 512.

#define B_SAMPLES 262144
#define HIDDEN    128
#define NUM_CODES 512
#define EMBED_DIM 256
#define NUM_INT   129     // HIDDEN + 1 intervals
#define MAXSEG    (NUM_INT * NUM_CODES)
#define NBUCK     4096
#define NBLK      512

// ---- workspace layout (byte offsets) ----
// 0       : t_sorted[128] double
// 2048    : code_out[512] double
// 8192    : env_cnt[129] int
// 12288   : gM[1] int
// 12544   : barrier counter[1] int   (zeroed via hipMemsetAsync each call)
// 16384   : gbuck[4097] int
// 36864   : surv[MAXSEG] uchar
// 106496  : Lx[MAXSEG] double
// 638976  : AB[MAXSEG] double2
// 1703936 : env_xs[MAXSEG] double
// 2236416 : env_idx[MAXSEG] int
// 2502656 : gxs[MAXSEG] double
// 3031040 : gval[MAXSEG] float2      -> total ~3.6 MB

struct TabS {   // phase 0
  double tloc[HIDDEN], ts[HIDDEN], wj[HIDDEN], bj[HIDDEN], sdw[EMBED_DIM];
};
struct EnvS {   // phase 1   (17408 B = union max)
  double2 sAB[NUM_CODES];
  double nl[4][64], dl[4][64], nu[4][64], du[4][64];
  int dd[4][64];
};
struct CmpS { double sA[NUM_CODES]; };                       // phase 2
struct Kg2S { int scount[NUM_INT], sj0[NUM_INT], soff[NUM_INT + 1]; }; // phase 3
union SMem { TabS t; EnvS e; CmpS c; Kg2S g; };

// Monotone-generation grid barrier: block's thread 0 releases its writes,
// bumps the counter, then acquire-spins until all NBLK blocks of this
// generation arrived. No reset -> no ABA. ~2us for 512 blocks.
__device__ __forceinline__ void gbar(int* c, int gen) {
  __syncthreads();
  if (threadIdx.x == 0) {
    __threadfence();                                   // release prior writes
    __hip_atomic_fetch_add(c, 1, __ATOMIC_RELEASE, __HIP_MEMORY_SCOPE_AGENT);
    const int target = NBLK * gen;
    while (__hip_atomic_load(c, __ATOMIC_ACQUIRE, __HIP_MEMORY_SCOPE_AGENT) < target)
      __builtin_amdgcn_s_sleep(1);
    __threadfence();                                   // acquire others' writes
  }
  __syncthreads();
}

__global__ void __launch_bounds__(256, 2) k_all(
    const float* __restrict__ x,   const float* __restrict__ w1,
    const float* __restrict__ b1,  const float* __restrict__ w2,
    const float* __restrict__ b2,  const float* __restrict__ emb,
    const float* __restrict__ decw, const float* __restrict__ decb,
    double* __restrict__ t_sorted, double* __restrict__ code_out,
    int* __restrict__ env_cnt, int* __restrict__ gM, int* __restrict__ gbuck,
    unsigned char* __restrict__ surv, double* __restrict__ Lx,
    double2* __restrict__ AB, double* __restrict__ env_xs,
    int* __restrict__ env_idx, double* __restrict__ gxs,
    float2* __restrict__ gval, float* __restrict__ out,
    float* __restrict__ idx_out, int* __restrict__ bar) {
  __shared__ SMem sm;
  const int blk = blockIdx.x, tid = threadIdx.x;

  // ---------- phase 0: thresholds + AB tables + code_out + env_cnt zero ----
  if (blk < 258) {                       // table task = blk (interval, half)
    if (tid < HIDDEN) {
      double w = (double)w1[tid], b = (double)b1[tid];
      double t = -b / w;
      if (!isfinite(t)) t = 1e30;
      t = fmin(fmax(t, -1e30), 1e30);
      sm.t.tloc[tid] = t;
    }
    __syncthreads();
    if (tid < HIDDEN) {                  // stable rank sort, O(128^2)
      double t = sm.t.tloc[tid];
      int r = 0;
      for (int k = 0; k < HIDDEN; ++k) {
        double tk = sm.t.tloc[k];
        r += (tk < t) || (tk == t && k < tid);
      }
      sm.t.ts[r] = t;
    }
    __syncthreads();
    if (blk == 0 && tid < HIDDEN) t_sorted[tid] = sm.t.ts[tid];
    const int i = blk >> 1;
    const int c = ((blk & 1) << 8) + tid;
    double xm;
    if (i == 0)           xm = sm.t.ts[0] - 1.0;
    else if (i == HIDDEN) xm = sm.t.ts[HIDDEN - 1] + 1.0;
    else                  xm = 0.5 * (sm.t.ts[i - 1] + sm.t.ts[i]);
    if (tid < HIDDEN) {
      double w = (double)w1[tid], b = (double)b1[tid];
      bool act = fma(w, xm, b) > 0.0;    // relu sign constant in open interval
      sm.t.wj[tid] = act ? w : 0.0;
      sm.t.bj[tid] = act ? b : 0.0;
    }
    __syncthreads();
    const float4* r4 = (const float4*)(w2 + c * HIDDEN);
    double A = 0.0, Bv = 0.0;
    #pragma unroll 8
    for (int q = 0; q < HIDDEN / 4; ++q) {
      const float4 v = r4[q];
      const int j = q * 4;
      A  = fma((double)v.x, sm.t.wj[j + 0], A);
      A  = fma((double)v.y, sm.t.wj[j + 1], A);
      A  = fma((double)v.z, sm.t.wj[j + 2], A);
      A  = fma((double)v.w, sm.t.wj[j + 3], A);
      Bv = fma((double)v.x, sm.t.bj[j + 0], Bv);
      Bv = fma((double)v.y, sm.t.bj[j + 1], Bv);
      Bv = fma((double)v.z, sm.t.bj[j + 2], Bv);
      Bv = fma((double)v.w, sm.t.bj[j + 3], Bv);
    }
    AB[(i << 9) + c] = make_double2(A, Bv + (double)b2[c]);
  } else if (blk < 260) {                // code_out, 2 blocks x 256 codes
    sm.t.sdw[tid] = (double)decw[tid];
    __syncthreads();
    const int c = (blk - 258) * 256 + tid;
    const float4* e4 = (const float4*)(emb + c * EMBED_DIM);
    double s = 0.0;
    #pragma unroll 8
    for (int q = 0; q < EMBED_DIM / 4; ++q) {
      const float4 v = e4[q];
      const int j = q * 4;
      s = fma((double)v.x, sm.t.sdw[j + 0], s);
      s = fma((double)v.y, sm.t.sdw[j + 1], s);
      s = fma((double)v.z, sm.t.sdw[j + 2], s);
      s = fma((double)v.w, sm.t.sdw[j + 3], s);
    }
    code_out[c] = s + (double)decb[0];
  } else if (blk == 260) {
    if (tid < NUM_INT) env_cnt[tid] = 0;
  }
  gbar(bar, 1);

  // ---------- phase 1: branchless pairwise envelope membership --------------
  // L as (nL,dL) dL>=0 (dL==0 => -inf); U as (nU,dU) dU<=0 (dU==0 => +inf).
  for (int T = blk; T < NUM_INT * 8; T += NBLK) {
    const int i = T >> 3, g = T & 7;
    const int w = tid >> 6, lane = tid & 63;
    const int c = (g << 6) + lane;
    __syncthreads();                     // protect LDS reuse across iterations
    const double2* row = AB + (i << 9);
    for (int t = tid; t < NUM_CODES; t += 256) sm.e.sAB[t] = row[t];
    __syncthreads();
    const double2 my = sm.e.sAB[c];
    double nL = -1.0, dL = 0.0, nU = -1.0, dU = 0.0;
    int dead = 0;
    const int k0 = w << 7;
    #pragma unroll 4
    for (int kk = 0; kk < 128; ++kk) {
      const int k = k0 + kk;
      const double2 o = sm.e.sAB[k];     // wave-uniform -> LDS broadcast
      const double d = my.x - o.x;
      const double n = o.y - my.y;       // x* = n/d
      const bool cL = (d > 0.0) && (n * dL > nL * d);
      const bool cU = (d < 0.0) && (n * dU < nU * d);
      nL = cL ? n : nL;  dL = cL ? d : dL;
      nU = cU ? n : nU;  dU = cU ? d : dU;
      dead |= (d == 0.0) && ((n > 0.0) || (n == 0.0 && k < c));
    }
    sm.e.nl[w][lane] = nL; sm.e.dl[w][lane] = dL;
    sm.e.nu[w][lane] = nU; sm.e.du[w][lane] = dU;
    sm.e.dd[w][lane] = dead;
    __syncthreads();
    if (tid < 64) {                      // wave 0 merges the 4 k-chunks
      #pragma unroll
      for (int wv = 1; wv < 4; ++wv) {
        double cn = sm.e.nl[wv][lane], cd = sm.e.dl[wv][lane];
        if (cn * dL > nL * cd) { nL = cn; dL = cd; }
        cn = sm.e.nu[wv][lane]; cd = sm.e.du[wv][lane];
        if (cn * dU < nU * cd) { nU = cn; dU = cd; }
        dead |= sm.e.dd[wv][lane];
      }
      const int sv = (!dead) && (dL == 0.0 || dU == 0.0 || (nL * dU > nU * dL));
      const int pair = (i << 9) + c;
      surv[pair] = (unsigned char)sv;
      Lx[pair]   = (dL == 0.0) ? -1e300 : nL / dL;
      const unsigned long long m = __ballot(sv);
      if (lane == 0) atomicAdd(&env_cnt[i], (int)__popcll(m));
    }
  }
  gbar(bar, 2);

  // ---------- phase 2: compact survivors, slope-sorted ----------------------
  for (int T = blk; T < 258; T += NBLK) {
    const int i = T >> 1;
    const int c = ((T & 1) << 8) + tid;
    const int base = i << 9;
    __syncthreads();
    for (int t = tid; t < NUM_CODES; t += 256)
      sm.c.sA[t] = surv[base + t] ? AB[base + t].x : 1e300;
    __syncthreads();
    const double myA = sm.c.sA[c];
    int rank = 0;
    #pragma unroll 8
    for (int k = 0; k < NUM_CODES; ++k) rank += (sm.c.sA[k] < myA) ? 1 : 0;
    if (surv[base + c]) {
      env_xs[base + rank]  = Lx[base + c];
      env_idx[base + rank] = c;
    }
  }
  gbar(bar, 3);

  // ---------- phase 3: flatten to global x-sorted table ---------------------
  if (blk < NUM_INT) {
    if (tid < NUM_INT) {
      const int ii = tid;
      const double tlo = (ii == 0) ? -1e300 : t_sorted[ii - 1];
      const double thi = (ii == NUM_INT - 1) ? 1e300 : t_sorted[ii];
      const int cnt = env_cnt[ii];
      const int base = ii << 9;
      int lo = 0, hi = cnt - 1;          // j0: largest j with xs <= tlo
      while (lo < hi) { int mid = (lo + hi + 1) >> 1; if (env_xs[base + mid] <= tlo) lo = mid; else hi = mid - 1; }
      const int j0 = lo;
      lo = 0; hi = cnt - 1;              // jend: largest j with xs < thi
      while (lo < hi) { int mid = (lo + hi + 1) >> 1; if (env_xs[base + mid] < thi) lo = mid; else hi = mid - 1; }
      sm.g.sj0[ii] = j0;
      sm.g.scount[ii] = max(0, lo - j0 + 1);   // 0 for zero-width intervals
    }
    __syncthreads();
    if (tid <= NUM_INT) sm.g.soff[tid] = (tid == 0) ? 0 : sm.g.scount[tid - 1];
    __syncthreads();
    for (int off = 1; off <= NUM_INT; off <<= 1) {   // Hillis-Steele prefix
      int v = 0;
      if (tid <= NUM_INT && tid >= off) v = sm.g.soff[tid - off];
      __syncthreads();
      if (tid <= NUM_INT) sm.g.soff[tid] += v;
      __syncthreads();
    }
    const int i = blk;
    const int off = sm.g.soff[i], j0 = sm.g.sj0[i], cnt_i = sm.g.scount[i];
    const int base = i << 9;
    const double tlo = (i == 0) ? -1e300 : t_sorted[i - 1];
    for (int k = tid; k < cnt_i; k += 256) {
      const int c = env_idx[base + j0 + k];
      gxs[off + k]  = (k == 0) ? tlo : env_xs[base + j0 + k];
      gval[off + k] = make_float2((float)code_out[c], (float)c);
    }
    if (i == 0 && tid == 0) gM[0] = sm.g.soff[NUM_INT];
  }
  gbar(bar, 4);

  // ---------- phase 4: bucket accelerator -----------------------------------
  if (blk < NBUCK / 256) {
    const int b = blk * 256 + tid;
    const int M = gM[0];
    const unsigned key = (unsigned)b << 20;
    const unsigned u = (key & 0x80000000u) ? (key ^ 0x80000000u) : ~key;
    const float xf = __uint_as_float(u);
    double xb;
    if (xf != xf) xb = (b >= NBUCK / 2) ? 1e300 : -1e300;  // NaN-prefix buckets
    else          xb = (double)xf;
    int lo = 0, hi = M - 1;
    while (lo < hi) { int mid = (lo + hi + 1) >> 1; if (gxs[mid] <= xb) lo = mid; else hi = mid - 1; }
    gbuck[b] = lo;
    if (b == 0) gbuck[NBUCK] = M - 1;
  }
  gbar(bar, 5);

  // ---------- phase 5: per-sample lookup (2 samples/thread, float2 I/O) -----
  {
    const int s = blk * 512 + tid * 2;
    const float2 xv2 = *(const float2*)(x + s);
    const float xs2[2] = {xv2.x, xv2.y};
    float o[2], id[2];
    #pragma unroll
    for (int k = 0; k < 2; ++k) {
      const float xf = xs2[k];
      const double xv = (double)xf;
      const unsigned u = __float_as_uint(xf);
      const unsigned key = (u & 0x80000000u) ? ~u : (u | 0x80000000u);
      const int b = key >> 20;
      int lo = gbuck[b], hi = gbuck[b + 1];
      while (lo < hi) {                  // rare: bucket spans >1 segment
        const int mid = (lo + hi + 1) >> 1;
        if (gxs[mid] <= xv) lo = mid; else hi = mid - 1;
      }
      const float2 v = gval[lo];
      o[k] = v.x; id[k] = v.y;
    }
    *(float2*)(out + s)     = make_float2(o[0], o[1]);
    *(float2*)(idx_out + s) = make_float2(id[0], id[1]);
  }
}

extern "C" void kernel_launch(void* const* d_in, const int* in_sizes, int n_in,
                              void* d_out, int out_size, void* d_ws, size_t ws_size,
                              hipStream_t stream) {
  const float* x    = (const float*)d_in[0];
  const float* w1   = (const float*)d_in[1];
  const float* b1   = (const float*)d_in[2];
  const float* w2   = (const float*)d_in[3];
  const float* b2   = (const float*)d_in[4];
  const float* emb  = (const float*)d_in[5];
  const float* decw = (const float*)d_in[6];
  const float* decb = (const float*)d_in[7];

  char* ws = (char*)d_ws;
  double*        t_sorted = (double*)        (ws + 0);
  double*        code_out = (double*)        (ws + 2048);
  int*           env_cnt  = (int*)           (ws + 8192);
  int*           gM       = (int*)           (ws + 12288);
  int*           bar      = (int*)           (ws + 12544);
  int*           gbuck    = (int*)           (ws + 16384);
  unsigned char* surv     = (unsigned char*) (ws + 36864);
  double*        Lx       = (double*)        (ws + 106496);
  double2*       AB       = (double2*)       (ws + 638976);
  double*        env_xs   = (double*)        (ws + 1703936);
  int*           env_idx  = (int*)           (ws + 2236416);
  double*        gxs      = (double*)        (ws + 2502656);
  float2*        gval     = (float2*)        (ws + 3031040);

  float* out  = (float*)d_out;
  float* idxo = out + B_SAMPLES;

  hipMemsetAsync(bar, 0, sizeof(int), stream);   // counter starts poisoned
  k_all<<<NBLK, 256, 0, stream>>>(x, w1, b1, w2, b2, emb, decw, decb,
                                  t_sorted, code_out, env_cnt, gM, gbuck,
                                  surv, Lx, AB, env_xs, env_idx, gxs, gval,
                                  out, idxo, bar);
}

// Round 8
// 129.780 us; speedup vs baseline: 3.6337x; 3.6337x over previous
//
#include <hip/hip_runtime.h>

// VQ-VAE forward: out = code_out[argmax_c(logits_c(x))], hard_idx = argmax.
// logits are piecewise-linear in scalar x (128 relu breakpoints). Build the
// per-interval UPPER ENVELOPE of the 512 affine logit lines (fp64-exact,
// branchless pairwise L/U-bound formulation); samples classify their interval
// (7 LDS steps) + short binary search in that interval's segment table.
// R6/R7 lesson: in-kernel grid barriers cost 50-80us EACH on gfx950 (XCD
// coherence point); kernel launch boundaries (~3us) are the cheap barrier.
// R8: 4 launches (prep fused into tables), env1 dep-chain split 2-way,
// map 2 samples/thread.

#define B_SAMPLES 262144
#define HIDDEN    128
#define NUM_CODES 512
#define EMBED_DIM 256
#define NUM_INT   129     // HIDDEN + 1 intervals
#define MAXSEG    (NUM_INT * NUM_CODES)

// ---- workspace layout (byte offsets) ----
// 0       : t_sorted[128] double
// 2048    : code_out[512] double
// 8192    : env_cnt[129] int
// 36864   : surv[MAXSEG] uchar
// 106496  : Lx[MAXSEG] double
// 638976  : AB[MAXSEG] double2
// 1703936 : env_xs[MAXSEG] double
// 2236416 : env_idx[MAXSEG] int      -> total ~2.5 MB

__device__ __forceinline__ int classify(const double* ts, double xv) {
  int lo = 0, hi = HIDDEN;   // first index with ts[idx] > xv
  while (lo < hi) { int mid = (lo + hi) >> 1; if (ts[mid] > xv) hi = mid; else lo = mid + 1; }
  return lo;
}

// L1: blocks 0..257 = per-interval affine tables (each block redundantly
// rank-sorts thresholds in LDS, ~1us); 258..259 = code_out; 260 = env_cnt=0.
__global__ void __launch_bounds__(256) k_stage0(
    const float* __restrict__ w1, const float* __restrict__ b1,
    const float* __restrict__ w2, const float* __restrict__ b2,
    const float* __restrict__ emb, const float* __restrict__ decw,
    const float* __restrict__ decb, double* __restrict__ t_sorted,
    double* __restrict__ code_out, int* __restrict__ env_cnt,
    double2* __restrict__ AB) {
  const int blk = blockIdx.x, tid = threadIdx.x;
  if (blk < 258) {
    __shared__ double tloc[HIDDEN], ts[HIDDEN], wj[HIDDEN], bj[HIDDEN];
    if (tid < HIDDEN) {
      double w = (double)w1[tid], b = (double)b1[tid];
      double t = -b / w;
      if (!isfinite(t)) t = 1e30;
      t = fmin(fmax(t, -1e30), 1e30);
      tloc[tid] = t;
    }
    __syncthreads();
    if (tid < HIDDEN) {                  // stable rank sort, O(128^2)
      double t = tloc[tid];
      int r = 0;
      for (int k = 0; k < HIDDEN; ++k) {
        double tk = tloc[k];
        r += (tk < t) || (tk == t && k < tid);
      }
      ts[r] = t;
    }
    __syncthreads();
    if (blk == 0 && tid < HIDDEN) t_sorted[tid] = ts[tid];
    const int i = blk >> 1;
    const int c = ((blk & 1) << 8) + tid;
    double xm;
    if (i == 0)           xm = ts[0] - 1.0;
    else if (i == HIDDEN) xm = ts[HIDDEN - 1] + 1.0;
    else                  xm = 0.5 * (ts[i - 1] + ts[i]);
    if (tid < HIDDEN) {
      double w = (double)w1[tid], b = (double)b1[tid];
      bool act = fma(w, xm, b) > 0.0;    // relu sign constant in open interval
      wj[tid] = act ? w : 0.0;
      bj[tid] = act ? b : 0.0;
    }
    __syncthreads();
    const float4* r4 = (const float4*)(w2 + c * HIDDEN);
    double A = 0.0, Bv = 0.0;
    #pragma unroll 8
    for (int q = 0; q < HIDDEN / 4; ++q) {
      const float4 v = r4[q];
      const int j = q * 4;
      A  = fma((double)v.x, wj[j + 0], A);
      A  = fma((double)v.y, wj[j + 1], A);
      A  = fma((double)v.z, wj[j + 2], A);
      A  = fma((double)v.w, wj[j + 3], A);
      Bv = fma((double)v.x, bj[j + 0], Bv);
      Bv = fma((double)v.y, bj[j + 1], Bv);
      Bv = fma((double)v.z, bj[j + 2], Bv);
      Bv = fma((double)v.w, bj[j + 3], Bv);
    }
    AB[(i << 9) + c] = make_double2(A, Bv + (double)b2[c]);
  } else if (blk < 260) {                // code_out: 2 blocks x 256 codes
    __shared__ double sdw[EMBED_DIM];
    sdw[tid] = (double)decw[tid];
    __syncthreads();
    const int c = (blk - 258) * 256 + tid;
    const float4* e4 = (const float4*)(emb + c * EMBED_DIM);
    double s = 0.0;
    #pragma unroll 8
    for (int q = 0; q < EMBED_DIM / 4; ++q) {
      const float4 v = e4[q];
      const int j = q * 4;
      s = fma((double)v.x, sdw[j + 0], s);
      s = fma((double)v.y, sdw[j + 1], s);
      s = fma((double)v.z, sdw[j + 2], s);
      s = fma((double)v.w, sdw[j + 3], s);
    }
    code_out[c] = s + (double)decb[0];
  } else {
    if (tid < NUM_INT) env_cnt[tid] = 0;
  }
}

// L2: branchless pairwise envelope membership (proven R2-R7). Dep chain
// split into even/odd accumulator pairs (halves the select-chain latency).
// L as (nL,dL) dL>=0 (dL==0 => -inf); U as (nU,dU) dU<=0 (dU==0 => +inf).
__global__ void __launch_bounds__(256) k_env1(const double2* __restrict__ AB,
                       unsigned char* __restrict__ surv, double* __restrict__ Lx,
                       int* __restrict__ env_cnt) {
  __shared__ double2 sAB[NUM_CODES];
  __shared__ double sNL[4][64], sDL[4][64], sNU[4][64], sDU[4][64];
  __shared__ int sDead[4][64];
  const int tid = threadIdx.x;
  const int i = blockIdx.x >> 3;
  const int g = blockIdx.x & 7;
  const int w = tid >> 6, lane = tid & 63;
  const int c = (g << 6) + lane;
  const double2* row = AB + (i << 9);
  for (int t = tid; t < NUM_CODES; t += 256) sAB[t] = row[t];
  __syncthreads();
  const double2 my = sAB[c];
  double nL0 = -1.0, dL0 = 0.0, nU0 = -1.0, dU0 = 0.0;
  double nL1 = -1.0, dL1 = 0.0, nU1 = -1.0, dU1 = 0.0;
  int dead = 0;
  const int k0 = w << 7;
  #pragma unroll 4
  for (int kk = 0; kk < 128; kk += 2) {
    {
      const int k = k0 + kk;
      const double2 o = sAB[k];          // wave-uniform -> LDS broadcast
      const double d = my.x - o.x;
      const double n = o.y - my.y;       // x* = n/d
      const bool cL = (d > 0.0) && (n * dL0 > nL0 * d);
      const bool cU = (d < 0.0) && (n * dU0 < nU0 * d);
      nL0 = cL ? n : nL0;  dL0 = cL ? d : dL0;
      nU0 = cU ? n : nU0;  dU0 = cU ? d : dU0;
      dead |= (d == 0.0) && ((n > 0.0) || (n == 0.0 && k < c));
    }
    {
      const int k = k0 + kk + 1;
      const double2 o = sAB[k];
      const double d = my.x - o.x;
      const double n = o.y - my.y;
      const bool cL = (d > 0.0) && (n * dL1 > nL1 * d);
      const bool cU = (d < 0.0) && (n * dU1 < nU1 * d);
      nL1 = cL ? n : nL1;  dL1 = cL ? d : dL1;
      nU1 = cU ? n : nU1;  dU1 = cU ? d : dU1;
      dead |= (d == 0.0) && ((n > 0.0) || (n == 0.0 && k < c));
    }
  }
  // merge odd set into even set (rule valid incl. 0-sentinels)
  if (nL1 * dL0 > nL0 * dL1) { nL0 = nL1; dL0 = dL1; }
  if (nU1 * dU0 < nU0 * dU1) { nU0 = nU1; dU0 = dU1; }
  sNL[w][lane] = nL0; sDL[w][lane] = dL0;
  sNU[w][lane] = nU0; sDU[w][lane] = dU0;
  sDead[w][lane] = dead;
  __syncthreads();
  if (tid < 64) {                        // wave 0 merges the 4 k-chunks
    double nL = sNL[0][lane], dL = sDL[0][lane];
    double nU = sNU[0][lane], dU = sDU[0][lane];
    int dd = sDead[0][lane];
    #pragma unroll
    for (int wv = 1; wv < 4; ++wv) {
      double cn = sNL[wv][lane], cd = sDL[wv][lane];
      if (cn * dL > nL * cd) { nL = cn; dL = cd; }
      cn = sNU[wv][lane]; cd = sDU[wv][lane];
      if (cn * dU < nU * cd) { nU = cn; dU = cd; }
      dd |= sDead[wv][lane];
    }
    // L < U with dL>=0, dU<=0: multiply by dL*dU (<0) flips: nL*dU > nU*dL
    const int sv = (!dd) && (dL == 0.0 || dU == 0.0 || (nL * dU > nU * dL));
    const int pair = (i << 9) + c;
    surv[pair] = (unsigned char)sv;
    Lx[pair]   = (dL == 0.0) ? -1e300 : nL / dL;
    const unsigned long long m = __ballot(sv);
    if (lane == 0) atomicAdd(&env_cnt[i], (int)__popcll(m));
  }
}

// L3: compact survivors into per-interval slope-sorted segment tables.
// rank = #survivors with smaller slope (survivor slopes are distinct).
__global__ void __launch_bounds__(256) k_env2(const double2* __restrict__ AB,
                       const unsigned char* __restrict__ surv,
                       const double* __restrict__ Lx,
                       double* __restrict__ env_xs, int* __restrict__ env_idx) {
  __shared__ double sA[NUM_CODES];
  const int tid = threadIdx.x;
  const int i = blockIdx.x >> 1;
  const int c = ((blockIdx.x & 1) << 8) + tid;
  const int base = i << 9;
  for (int t = tid; t < NUM_CODES; t += 256)
    sA[t] = surv[base + t] ? AB[base + t].x : 1e300;
  __syncthreads();
  const double myA = sA[c];
  int rank = 0;
  #pragma unroll 8
  for (int k = 0; k < NUM_CODES; ++k) rank += (sA[k] < myA) ? 1 : 0;
  if (surv[base + c]) {
    env_xs[base + rank]  = Lx[base + c];
    env_idx[base + rank] = c;
  }
}

// L4: per-sample lookup: 7-step LDS classify + ~5-step binary search in the
// interval's segment table (env_xs in L2). 2 samples/thread, float2 I/O --
// the two dependent chains interleave. Unreachable head segments (xs<=tlo)
// are harmless: x > tlo steers the search past them.
__global__ void __launch_bounds__(256) k_map(const float* __restrict__ x,
                       const double* __restrict__ t_sorted,
                       const int* __restrict__ env_cnt,
                       const double* __restrict__ env_xs,
                       const int* __restrict__ env_idx,
                       const double* __restrict__ code_out,
                       float* __restrict__ out, float* __restrict__ idx_out) {
  __shared__ double ts[HIDDEN];
  __shared__ double sco[NUM_CODES];
  __shared__ int scnt[NUM_INT];
  const int tid = threadIdx.x;
  if (tid < HIDDEN) ts[tid] = t_sorted[tid];
  if (tid < NUM_INT) scnt[tid] = env_cnt[tid];
  for (int t = tid; t < NUM_CODES; t += 256) sco[t] = code_out[t];
  __syncthreads();
  const int s = blockIdx.x * 512 + tid * 2;
  const float2 xv2 = *(const float2*)(x + s);
  const float xs2[2] = {xv2.x, xv2.y};
  float o[2], id[2];
  #pragma unroll
  for (int k = 0; k < 2; ++k) {
    const double xv = (double)xs2[k];
    const int i = classify(ts, xv);
    const int base = i << 9;
    int lo = 0, hi = scnt[i] - 1;
    while (lo < hi) {                    // largest j with xs[j] <= xv
      const int mid = (lo + hi + 1) >> 1;
      if (env_xs[base + mid] <= xv) lo = mid; else hi = mid - 1;
    }
    const int ci = env_idx[base + lo];
    o[k]  = (float)sco[ci];
    id[k] = (float)ci;
  }
  *(float2*)(out + s)     = make_float2(o[0], o[1]);
  *(float2*)(idx_out + s) = make_float2(id[0], id[1]);
}

extern "C" void kernel_launch(void* const* d_in, const int* in_sizes, int n_in,
                              void* d_out, int out_size, void* d_ws, size_t ws_size,
                              hipStream_t stream) {
  const float* x    = (const float*)d_in[0];
  const float* w1   = (const float*)d_in[1];
  const float* b1   = (const float*)d_in[2];
  const float* w2   = (const float*)d_in[3];
  const float* b2   = (const float*)d_in[4];
  const float* emb  = (const float*)d_in[5];
  const float* decw = (const float*)d_in[6];
  const float* decb = (const float*)d_in[7];

  char* ws = (char*)d_ws;
  double*        t_sorted = (double*)        (ws + 0);
  double*        code_out = (double*)        (ws + 2048);
  int*           env_cnt  = (int*)           (ws + 8192);
  unsigned char* surv     = (unsigned char*) (ws + 36864);
  double*        Lx       = (double*)        (ws + 106496);
  double2*       AB       = (double2*)       (ws + 638976);
  double*        env_xs   = (double*)        (ws + 1703936);
  int*           env_idx  = (int*)           (ws + 2236416);

  float* out  = (float*)d_out;
  float* idxo = out + B_SAMPLES;

  k_stage0<<<261,             256, 0, stream>>>(w1, b1, w2, b2, emb, decw, decb,
                                                t_sorted, code_out, env_cnt, AB);
  k_env1  <<<NUM_INT * 8,     256, 0, stream>>>(AB, surv, Lx, env_cnt);
  k_env2  <<<NUM_INT * 2,     256, 0, stream>>>(AB, surv, Lx, env_xs, env_idx);
  k_map   <<<B_SAMPLES / 512, 256, 0, stream>>>(x, t_sorted, env_cnt, env_xs,
                                                env_idx, code_out, out, idxo);
}